// Round 1
// baseline (2075.919 us; speedup 1.0000x reference)
//
#include <hip/hip_runtime.h>
#include <hip/hip_bf16.h>

#define N_NODES 50000
#define T_SEQ 24
#define D_IN 16
#define H_DIM 64
#define SD 9
#define E_EDGES 1600000
#define NUM_GRAPHS 500

__device__ __forceinline__ float fsig(float x) { return 1.0f / (1.0f + __expf(-x)); }
__device__ __forceinline__ float ftanh(float x) { return 1.0f - 2.0f / (1.0f + __expf(2.0f * x)); }

// ---------------------------------------------------------------------------
// LSTM: block = 256 threads = 64 nodes x 4 gate-quarters.
// h double-buffered in LDS [j][node] (lane=node -> conflict-free), c in LDS.
// Each thread owns 16 hidden units of one node; one barrier per timestep.
// Weights accessed at wave-uniform addresses (readfirstlane) -> s_load.
// ---------------------------------------------------------------------------
__global__ __launch_bounds__(256) void lstm_kernel(
    const float* __restrict__ x,
    const float* __restrict__ W_ih, const float* __restrict__ W_hh,
    const float* __restrict__ b_ih, const float* __restrict__ b_hh,
    float* __restrict__ hout)
{
    __shared__ float h_lds[2][H_DIM][64];
    __shared__ float c_lds[H_DIM][64];

    const int tid = threadIdx.x;
    const int node_l = tid & 63;
    const int q = __builtin_amdgcn_readfirstlane(tid >> 6);  // wave-uniform quarter
    const int n = blockIdx.x * 64 + node_l;
    const int n_c = (n < N_NODES) ? n : (N_NODES - 1);
    const float* xn = x + (size_t)n_c * (T_SEQ * D_IN);

#pragma unroll
    for (int k = 0; k < 16; k++) {
        h_lds[0][q * 16 + k][node_l] = 0.0f;
        c_lds[q * 16 + k][node_l] = 0.0f;
    }
    __syncthreads();

    int cur = 0;
    for (int t = 0; t < T_SEQ; t++) {
        // per-node input row (16 floats)
        float xr[D_IN];
#pragma unroll
        for (int d = 0; d < D_IN; d += 4) {
            float4 v = *reinterpret_cast<const float4*>(xn + t * D_IN + d);
            xr[d] = v.x; xr[d + 1] = v.y; xr[d + 2] = v.z; xr[d + 3] = v.w;
        }
        // previous hidden state -> registers (static indexing)
        float hreg[H_DIM];
#pragma unroll
        for (int j = 0; j < H_DIM; j++) hreg[j] = h_lds[cur][j][node_l];

#pragma unroll 1
        for (int kk = 0; kk < 16; kk++) {
            const int k = q * 16 + kk;  // wave-uniform
            float pi = b_ih[k]       + b_hh[k];
            float pf = b_ih[64 + k]  + b_hh[64 + k];
            float pg = b_ih[128 + k] + b_hh[128 + k];
            float po = b_ih[192 + k] + b_hh[192 + k];
            const float* wi = W_ih + k * D_IN;
            const float* wh = W_hh + k * H_DIM;
#pragma unroll
            for (int d = 0; d < D_IN; d++) {
                const float xv = xr[d];
                pi += wi[d] * xv;
                pf += wi[64 * D_IN + d] * xv;
                pg += wi[128 * D_IN + d] * xv;
                po += wi[192 * D_IN + d] * xv;
            }
#pragma unroll
            for (int j = 0; j < H_DIM; j++) {
                const float hv = hreg[j];
                pi += wh[j] * hv;
                pf += wh[64 * H_DIM + j] * hv;
                pg += wh[128 * H_DIM + j] * hv;
                po += wh[192 * H_DIM + j] * hv;
            }
            const float ig = fsig(pi);
            const float fg = fsig(pf);
            const float gg = ftanh(pg);
            const float og = fsig(po);
            const float cv = fg * c_lds[k][node_l] + ig * gg;
            c_lds[k][node_l] = cv;
            h_lds[cur ^ 1][k][node_l] = og * ftanh(cv);
        }
        __syncthreads();
        cur ^= 1;
    }

    if (n < N_NODES) {
#pragma unroll
        for (int k = 0; k < 16; k++)
            hout[(size_t)n * H_DIM + q * 16 + k] = h_lds[cur][q * 16 + k][node_l];
    }
}

// ---------------------------------------------------------------------------
// Degree / normalization
// ---------------------------------------------------------------------------
__global__ void init_deg(float* __restrict__ deg) {
    int i = blockIdx.x * 256 + threadIdx.x;
    if (i < N_NODES) deg[i] = 1.0f;  // self-loop
}

__global__ void count_deg(const int* __restrict__ ei, float* __restrict__ deg) {
    int e = blockIdx.x * 256 + threadIdx.x;
    if (e < E_EDGES) {
        int c = ei[E_EDGES + e];  // col = dst
        if ((unsigned)c < N_NODES) atomicAdd(&deg[c], 1.0f);
    }
}

__global__ void make_dis(float* __restrict__ dis) {
    int i = blockIdx.x * 256 + threadIdx.x;
    if (i < N_NODES) dis[i] = rsqrtf(dis[i]);  // deg >= 1 always
}

// ---------------------------------------------------------------------------
// l1: z[n][o] = b[o] + sum_j W[o][j]*h[n][j] + sum_j W[o][64+j]*sdi[n][j]
// ---------------------------------------------------------------------------
__global__ void l1_kernel(const float* __restrict__ h, const float* __restrict__ sdi,
                          const float* __restrict__ W, const float* __restrict__ b,
                          float* __restrict__ z)
{
    int idx = blockIdx.x * 256 + threadIdx.x;
    int n = idx >> 6, o = idx & 63;
    if (n >= N_NODES) return;
    const float* hr = h + (size_t)n * 64;
    const float* sr = sdi + (size_t)n * SD;
    const float* wr = W + o * (H_DIM + SD);
    float acc = b[o];
#pragma unroll
    for (int j = 0; j < 64; j++) acc += wr[j] * hr[j];
#pragma unroll
    for (int j = 0; j < SD; j++) acc += wr[64 + j] * sr[j];
    z[idx] = acc;
}

// m[n][o] = dis[n] * sum_j z[n][j] * W[o][j]
__global__ void gcn_xform(const float* __restrict__ z, const float* __restrict__ W,
                          const float* __restrict__ dis, float* __restrict__ m)
{
    int idx = blockIdx.x * 256 + threadIdx.x;
    int n = idx >> 6, o = idx & 63;
    if (n >= N_NODES) return;
    const float* zr = z + (size_t)n * 64;
    const float* wr = W + o * 64;
    float acc = 0.0f;
#pragma unroll
    for (int j = 0; j < 64; j++) acc += wr[j] * zr[j];
    m[idx] = acc * dis[n];
}

// wave per 16 edges, lane = feature: acc[col][f] += m[row][f]
__global__ void scatter64(const int* __restrict__ ei, const float* __restrict__ m,
                          float* __restrict__ acc)
{
    const int EPW = 16;
    int wid = (blockIdx.x * blockDim.x + threadIdx.x) >> 6;
    int f = threadIdx.x & 63;
    int e0 = wid * EPW;
    int e1 = min(e0 + EPW, E_EDGES);
    for (int e = e0; e < e1; e++) {
        int r = ei[e];
        int cd = ei[E_EDGES + e];
        if ((unsigned)r < N_NODES && (unsigned)cd < N_NODES)
            atomicAdd(&acc[(size_t)cd * 64 + f], m[(size_t)r * 64 + f]);
    }
}

// z1 = relu(dis[n]*(acc + m) + b)   (self-loop term folded in via m)
__global__ void fin1(const float* __restrict__ accb, const float* __restrict__ m,
                     const float* __restrict__ dis, const float* __restrict__ b,
                     float* __restrict__ z1)
{
    int idx = blockIdx.x * 256 + threadIdx.x;
    int n = idx >> 6, o = idx & 63;
    if (n >= N_NODES) return;
    float v = dis[n] * (accb[idx] + m[idx]) + b[o];
    z1[idx] = v > 0.0f ? v : 0.0f;
}

// s2[n] = dis[n] * dot(z1[n], W2row)
__global__ void gcn2_xform(const float* __restrict__ z1, const float* __restrict__ W2,
                           const float* __restrict__ dis, float* __restrict__ s2)
{
    int n = blockIdx.x * 256 + threadIdx.x;
    if (n >= N_NODES) return;
    const float* zr = z1 + (size_t)n * 64;
    float acc = 0.0f;
#pragma unroll
    for (int j = 0; j < 64; j += 4) {
        float4 v = *reinterpret_cast<const float4*>(zr + j);
        acc += v.x * W2[j] + v.y * W2[j + 1] + v.z * W2[j + 2] + v.w * W2[j + 3];
    }
    s2[n] = acc * dis[n];
}

__global__ void scatter1f(const int* __restrict__ ei, const float* __restrict__ s2,
                          float* __restrict__ acc2)
{
    int e = blockIdx.x * 256 + threadIdx.x;
    if (e < E_EDGES) {
        int r = ei[e];
        int cd = ei[E_EDGES + e];
        if ((unsigned)r < N_NODES && (unsigned)cd < N_NODES)
            atomicAdd(&acc2[cd], s2[r]);
    }
}

__global__ void finpool(const float* __restrict__ acc2, const float* __restrict__ s2,
                        const float* __restrict__ dis, const float* __restrict__ b2,
                        const int* __restrict__ batch,
                        float* __restrict__ gsum, float* __restrict__ gcnt)
{
    int n = blockIdx.x * 256 + threadIdx.x;
    if (n >= N_NODES) return;
    float z2 = dis[n] * (acc2[n] + s2[n]) + b2[0];
    int g = batch[n];
    if ((unsigned)g < NUM_GRAPHS) {
        atomicAdd(&gsum[g], z2);
        atomicAdd(&gcnt[g], 1.0f);
    }
}

__global__ void pooldiv(const float* __restrict__ gsum, const float* __restrict__ gcnt,
                        float* __restrict__ out)
{
    int g = blockIdx.x * 256 + threadIdx.x;
    if (g < NUM_GRAPHS) out[g] = gsum[g] / fmaxf(gcnt[g], 1.0f);
}

// ---------------------------------------------------------------------------
extern "C" void kernel_launch(void* const* d_in, const int* in_sizes, int n_in,
                              void* d_out, int out_size, void* d_ws, size_t ws_size,
                              hipStream_t stream)
{
    const float* x     = (const float*)d_in[0];
    const float* sdi   = (const float*)d_in[1];
    const int*   ei    = (const int*)d_in[2];
    const int*   batch = (const int*)d_in[3];
    const float* W_ih  = (const float*)d_in[4];
    const float* W_hh  = (const float*)d_in[5];
    const float* b_ih  = (const float*)d_in[6];
    const float* b_hh  = (const float*)d_in[7];
    const float* l1_W  = (const float*)d_in[8];
    const float* l1_b  = (const float*)d_in[9];
    const float* g1_W  = (const float*)d_in[10];
    const float* g1_b  = (const float*)d_in[11];
    const float* g2_W  = (const float*)d_in[12];
    const float* g2_b  = (const float*)d_in[13];
    float* out = (float*)d_out;

    // workspace layout (floats): A(3.2M) B(3.2M) C(3.2M) dis(50K) s2(50K) acc2(50K) gsum(500) gcnt(500)
    float* ws   = (float*)d_ws;
    float* A    = ws;                 // lstm h, then reused as gcn1 scatter accumulator
    float* B    = ws + 3200000;       // z, then z1 (in place)
    float* C    = ws + 6400000;       // m = dis * (z @ W1^T)
    float* dis  = ws + 9600000;
    float* s2   = dis + 50000;
    float* acc2 = s2 + 50000;         // contiguous zero region: acc2+gsum+gcnt
    float* gsum = acc2 + 50000;
    float* gcnt = gsum + 500;

    const int nodeBlocks  = (N_NODES + 255) / 256;          // 196
    const int featBlocks  = (N_NODES * 64 + 255) / 256;     // 12500
    const int edgeBlocks  = (E_EDGES + 255) / 256;          // 6250
    const int scatBlocks  = ((E_EDGES + 15) / 16 * 64 + 255) / 256;  // 25000

    // 1. LSTM -> A
    lstm_kernel<<<(N_NODES + 63) / 64, 256, 0, stream>>>(x, W_ih, W_hh, b_ih, b_hh, A);

    // 2-4. degree -> dis (in place)
    init_deg<<<nodeBlocks, 256, 0, stream>>>(dis);
    count_deg<<<edgeBlocks, 256, 0, stream>>>(ei, dis);
    make_dis<<<nodeBlocks, 256, 0, stream>>>(dis);

    // 5. l1: (A, sdi) -> B
    l1_kernel<<<featBlocks, 256, 0, stream>>>(A, sdi, l1_W, l1_b, B);

    // 6. A becomes scatter accumulator
    hipMemsetAsync(A, 0, (size_t)N_NODES * 64 * sizeof(float), stream);
    hipMemsetAsync(acc2, 0, (size_t)(50000 + 500 + 500) * sizeof(float), stream);

    // 7. m = dis * (B @ W1^T) -> C
    gcn_xform<<<featBlocks, 256, 0, stream>>>(B, g1_W, dis, C);

    // 8. scatter: A[col] += C[row]
    scatter64<<<scatBlocks, 256, 0, stream>>>(ei, C, A);

    // 9. z1 = relu(dis*(A + C) + b1) -> B (in place over z)
    fin1<<<featBlocks, 256, 0, stream>>>(A, C, dis, g1_b, B);

    // 10. s2 = dis * (B @ W2^T)
    gcn2_xform<<<nodeBlocks, 256, 0, stream>>>(B, g2_W, dis, s2);

    // 11. scalar scatter
    scatter1f<<<edgeBlocks, 256, 0, stream>>>(ei, s2, acc2);

    // 12. finalize z2 + pool
    finpool<<<nodeBlocks, 256, 0, stream>>>(acc2, s2, dis, g2_b, batch, gsum, gcnt);
    pooldiv<<<2, 256, 0, stream>>>(gsum, gcnt, out);
}

// Round 2
// 1106.398 us; speedup vs baseline: 1.8763x; 1.8763x over previous
//
#include <hip/hip_runtime.h>
#include <hip/hip_bf16.h>

#define N_NODES 50000
#define T_SEQ 24
#define D_IN 16
#define H_DIM 64
#define SD 9
#define E_EDGES 1600000
#define NUM_GRAPHS 500

typedef _Float16 half8 __attribute__((ext_vector_type(8)));
typedef float floatx4 __attribute__((ext_vector_type(4)));

__device__ __forceinline__ float fsig(float x) { return 1.0f / (1.0f + __expf(-x)); }
__device__ __forceinline__ float ftanh(float x) { return 1.0f - 2.0f / (1.0f + __expf(2.0f * x)); }

// ---------------------------------------------------------------------------
// MFMA LSTM. Block = 64 nodes, 4 waves. Wave w computes units [16w, 16w+16)
// for all 4 gates (col-tile = gate), so i/f/g/o of a unit live in one lane.
// Per timestep: G[64,256] = [H | x_t] @ [W_hh^T ; W_ih^T] via 16x16x32 f16
// MFMA (K-tiles: h 0-31, h 32-63, x 0-15|pad). Weights -> f16 B-fragments in
// VGPRs once, reused for all 24 steps. h in LDS f16 with XOR block-swizzle
// (2 lanes/bank on ds_read_b128 = free). c in registers (D-fragment layout).
// ---------------------------------------------------------------------------
__global__ __launch_bounds__(256, 2) void lstm_mfma(
    const float* __restrict__ x,
    const float* __restrict__ W_ih, const float* __restrict__ W_hh,
    const float* __restrict__ b_ih, const float* __restrict__ b_hh,
    float* __restrict__ hout)
{
    __shared__ _Float16 hbuf[64 * 64];   // [node][swizzled unit]

    const int tid  = threadIdx.x;
    const int lane = tid & 63;
    const int w    = tid >> 6;      // wave id: unit block
    const int lr   = lane & 15;     // row/col within 16x16 tile
    const int lg   = lane >> 4;     // k-group (A/B) or row-group (D)
    const int nbase = blockIdx.x * 64;

    // ---- B fragments (weights), loaded once ----
    // B[k][col]: lane holds col=lr of col-tile ct, k = kt*32 + 8*lg + e.
    // global gate row r = ct*64 + w*16 + lr.
    half8 bw[4][3];
    float bias[4];
#pragma unroll
    for (int ct = 0; ct < 4; ct++) {
        const int r = ct * 64 + w * 16 + lr;
        bias[ct] = b_ih[r] + b_hh[r];
#pragma unroll
        for (int kt = 0; kt < 2; kt++) {
            const float* p = W_hh + r * 64 + kt * 32 + 8 * lg;
            half8 f;
#pragma unroll
            for (int e = 0; e < 8; e++) f[e] = (_Float16)p[e];
            bw[ct][kt] = f;
        }
        half8 f = {(_Float16)0, (_Float16)0, (_Float16)0, (_Float16)0,
                   (_Float16)0, (_Float16)0, (_Float16)0, (_Float16)0};
        if (lg < 2) {  // k-16*4 = d in [0,16)
            const float* p = W_ih + r * 16 + 8 * lg;
#pragma unroll
            for (int e = 0; e < 8; e++) f[e] = (_Float16)p[e];
        }
        bw[ct][2] = f;
    }

    // zero h state
    for (int i = tid; i < 64 * 64; i += 256) hbuf[i] = (_Float16)0.0f;
    __syncthreads();

    float c_reg[4][4];  // [row-tile][reg] ; node = 16*rt + 4*lg + j
#pragma unroll
    for (int rt = 0; rt < 4; rt++)
#pragma unroll
        for (int j = 0; j < 4; j++) c_reg[rt][j] = 0.0f;

    for (int t = 0; t < T_SEQ; t++) {
        // ---- x-part A fragments from global (issued early to hide latency)
        half8 ax[4];
#pragma unroll
        for (int rt = 0; rt < 4; rt++) {
            half8 f = {(_Float16)0, (_Float16)0, (_Float16)0, (_Float16)0,
                       (_Float16)0, (_Float16)0, (_Float16)0, (_Float16)0};
            if (lg < 2) {
                int n = nbase + 16 * rt + lr;
                if (n >= N_NODES) n = N_NODES - 1;
                const float* p = x + ((size_t)n * T_SEQ + t) * D_IN + 8 * lg;
                const float4 v0 = *reinterpret_cast<const float4*>(p);
                const float4 v1 = *reinterpret_cast<const float4*>(p + 4);
                f[0] = (_Float16)v0.x; f[1] = (_Float16)v0.y;
                f[2] = (_Float16)v0.z; f[3] = (_Float16)v0.w;
                f[4] = (_Float16)v1.x; f[5] = (_Float16)v1.y;
                f[6] = (_Float16)v1.z; f[7] = (_Float16)v1.w;
            }
            ax[rt] = f;
        }

        // ---- accumulators init = bias (splat over rows)
        floatx4 acc[4][4];
#pragma unroll
        for (int rt = 0; rt < 4; rt++)
#pragma unroll
            for (int ct = 0; ct < 4; ct++) {
                floatx4 a = {bias[ct], bias[ct], bias[ct], bias[ct]};
                acc[rt][ct] = a;
            }

        // ---- h-part MFMAs (A from LDS)
#pragma unroll
        for (int kt = 0; kt < 2; kt++) {
            half8 ah[4];
#pragma unroll
            for (int rt = 0; rt < 4; rt++) {
                const int n = 16 * rt + lr;
                const int ub = 4 * kt + lg;
                ah[rt] = *reinterpret_cast<const half8*>(
                    &hbuf[n * 64 + 8 * (ub ^ (n & 7))]);
            }
#pragma unroll
            for (int rt = 0; rt < 4; rt++)
#pragma unroll
                for (int ct = 0; ct < 4; ct++)
                    acc[rt][ct] = __builtin_amdgcn_mfma_f32_16x16x32_f16(
                        ah[rt], bw[ct][kt], acc[rt][ct], 0, 0, 0);
        }
        // ---- x-part MFMAs
#pragma unroll
        for (int rt = 0; rt < 4; rt++)
#pragma unroll
            for (int ct = 0; ct < 4; ct++)
                acc[rt][ct] = __builtin_amdgcn_mfma_f32_16x16x32_f16(
                    ax[rt], bw[ct][2], acc[rt][ct], 0, 0, 0);

        __syncthreads();  // all LDS reads of h done before overwrite

        // ---- elementwise gate update; write h_new back to LDS
        const int u = w * 16 + lr;
#pragma unroll
        for (int rt = 0; rt < 4; rt++) {
#pragma unroll
            for (int j = 0; j < 4; j++) {
                const float pi = acc[rt][0][j];
                const float pf = acc[rt][1][j];
                const float pg = acc[rt][2][j];
                const float po = acc[rt][3][j];
                const float ig = fsig(pi);
                const float fg = fsig(pf);
                const float gg = ftanh(pg);
                const float og = fsig(po);
                const float cv = fg * c_reg[rt][j] + ig * gg;
                c_reg[rt][j] = cv;
                const float hv = og * ftanh(cv);
                const int n = 16 * rt + 4 * lg + j;
                hbuf[n * 64 + (u & 7) + 8 * ((u >> 3) ^ (n & 7))] = (_Float16)hv;
                if (t == T_SEQ - 1) {
                    const int gn = nbase + n;
                    if (gn < N_NODES) hout[(size_t)gn * H_DIM + u] = hv;
                }
            }
        }
        __syncthreads();  // h_new visible before next step's reads
    }
}

// ---------------------------------------------------------------------------
// Degree / normalization
// ---------------------------------------------------------------------------
__global__ void init_deg(float* __restrict__ deg) {
    int i = blockIdx.x * 256 + threadIdx.x;
    if (i < N_NODES) deg[i] = 1.0f;  // self-loop
}

__global__ void count_deg(const int* __restrict__ ei, float* __restrict__ deg) {
    int e = blockIdx.x * 256 + threadIdx.x;
    if (e < E_EDGES) {
        int c = ei[E_EDGES + e];
        if ((unsigned)c < N_NODES) atomicAdd(&deg[c], 1.0f);
    }
}

__global__ void make_dis(float* __restrict__ dis) {
    int i = blockIdx.x * 256 + threadIdx.x;
    if (i < N_NODES) dis[i] = rsqrtf(dis[i]);
}

// ---------------------------------------------------------------------------
__global__ void l1_kernel(const float* __restrict__ h, const float* __restrict__ sdi,
                          const float* __restrict__ W, const float* __restrict__ b,
                          float* __restrict__ z)
{
    int idx = blockIdx.x * 256 + threadIdx.x;
    int n = idx >> 6, o = idx & 63;
    if (n >= N_NODES) return;
    const float* hr = h + (size_t)n * 64;
    const float* sr = sdi + (size_t)n * SD;
    const float* wr = W + o * (H_DIM + SD);
    float acc = b[o];
#pragma unroll
    for (int j = 0; j < 64; j++) acc += wr[j] * hr[j];
#pragma unroll
    for (int j = 0; j < SD; j++) acc += wr[64 + j] * sr[j];
    z[idx] = acc;
}

__global__ void gcn_xform(const float* __restrict__ z, const float* __restrict__ W,
                          const float* __restrict__ dis, float* __restrict__ m)
{
    int idx = blockIdx.x * 256 + threadIdx.x;
    int n = idx >> 6, o = idx & 63;
    if (n >= N_NODES) return;
    const float* zr = z + (size_t)n * 64;
    const float* wr = W + o * 64;
    float acc = 0.0f;
#pragma unroll
    for (int j = 0; j < 64; j++) acc += wr[j] * zr[j];
    m[idx] = acc * dis[n];
}

__global__ void scatter64(const int* __restrict__ ei, const float* __restrict__ m,
                          float* __restrict__ acc)
{
    const int EPW = 16;
    int wid = (blockIdx.x * blockDim.x + threadIdx.x) >> 6;
    int f = threadIdx.x & 63;
    int e0 = wid * EPW;
    int e1 = min(e0 + EPW, E_EDGES);
    for (int e = e0; e < e1; e++) {
        int r = ei[e];
        int cd = ei[E_EDGES + e];
        if ((unsigned)r < N_NODES && (unsigned)cd < N_NODES)
            atomicAdd(&acc[(size_t)cd * 64 + f], m[(size_t)r * 64 + f]);
    }
}

__global__ void fin1(const float* __restrict__ accb, const float* __restrict__ m,
                     const float* __restrict__ dis, const float* __restrict__ b,
                     float* __restrict__ z1)
{
    int idx = blockIdx.x * 256 + threadIdx.x;
    int n = idx >> 6, o = idx & 63;
    if (n >= N_NODES) return;
    float v = dis[n] * (accb[idx] + m[idx]) + b[o];
    z1[idx] = v > 0.0f ? v : 0.0f;
}

__global__ void gcn2_xform(const float* __restrict__ z1, const float* __restrict__ W2,
                           const float* __restrict__ dis, float* __restrict__ s2)
{
    int n = blockIdx.x * 256 + threadIdx.x;
    if (n >= N_NODES) return;
    const float* zr = z1 + (size_t)n * 64;
    float acc = 0.0f;
#pragma unroll
    for (int j = 0; j < 64; j += 4) {
        float4 v = *reinterpret_cast<const float4*>(zr + j);
        acc += v.x * W2[j] + v.y * W2[j + 1] + v.z * W2[j + 2] + v.w * W2[j + 3];
    }
    s2[n] = acc * dis[n];
}

__global__ void scatter1f(const int* __restrict__ ei, const float* __restrict__ s2,
                          float* __restrict__ acc2)
{
    int e = blockIdx.x * 256 + threadIdx.x;
    if (e < E_EDGES) {
        int r = ei[e];
        int cd = ei[E_EDGES + e];
        if ((unsigned)r < N_NODES && (unsigned)cd < N_NODES)
            atomicAdd(&acc2[cd], s2[r]);
    }
}

__global__ void finpool(const float* __restrict__ acc2, const float* __restrict__ s2,
                        const float* __restrict__ dis, const float* __restrict__ b2,
                        const int* __restrict__ batch,
                        float* __restrict__ gsum, float* __restrict__ gcnt)
{
    int n = blockIdx.x * 256 + threadIdx.x;
    if (n >= N_NODES) return;
    float z2 = dis[n] * (acc2[n] + s2[n]) + b2[0];
    int g = batch[n];
    if ((unsigned)g < NUM_GRAPHS) {
        atomicAdd(&gsum[g], z2);
        atomicAdd(&gcnt[g], 1.0f);
    }
}

__global__ void pooldiv(const float* __restrict__ gsum, const float* __restrict__ gcnt,
                        float* __restrict__ out)
{
    int g = blockIdx.x * 256 + threadIdx.x;
    if (g < NUM_GRAPHS) out[g] = gsum[g] / fmaxf(gcnt[g], 1.0f);
}

// ---------------------------------------------------------------------------
extern "C" void kernel_launch(void* const* d_in, const int* in_sizes, int n_in,
                              void* d_out, int out_size, void* d_ws, size_t ws_size,
                              hipStream_t stream)
{
    const float* x     = (const float*)d_in[0];
    const float* sdi   = (const float*)d_in[1];
    const int*   ei    = (const int*)d_in[2];
    const int*   batch = (const int*)d_in[3];
    const float* W_ih  = (const float*)d_in[4];
    const float* W_hh  = (const float*)d_in[5];
    const float* b_ih  = (const float*)d_in[6];
    const float* b_hh  = (const float*)d_in[7];
    const float* l1_W  = (const float*)d_in[8];
    const float* l1_b  = (const float*)d_in[9];
    const float* g1_W  = (const float*)d_in[10];
    const float* g1_b  = (const float*)d_in[11];
    const float* g2_W  = (const float*)d_in[12];
    const float* g2_b  = (const float*)d_in[13];
    float* out = (float*)d_out;

    float* ws   = (float*)d_ws;
    float* A    = ws;                 // lstm h, then gcn1 scatter accumulator
    float* B    = ws + 3200000;       // z, then z1 (in place)
    float* C    = ws + 6400000;       // m = dis * (z @ W1^T)
    float* dis  = ws + 9600000;
    float* s2   = dis + 50000;
    float* acc2 = s2 + 50000;
    float* gsum = acc2 + 50000;
    float* gcnt = gsum + 500;

    const int nodeBlocks  = (N_NODES + 255) / 256;
    const int featBlocks  = (N_NODES * 64 + 255) / 256;
    const int edgeBlocks  = (E_EDGES + 255) / 256;
    const int scatBlocks  = ((E_EDGES + 15) / 16 * 64 + 255) / 256;

    // 1. LSTM -> A
    lstm_mfma<<<(N_NODES + 63) / 64, 256, 0, stream>>>(x, W_ih, W_hh, b_ih, b_hh, A);

    // 2-4. degree -> dis
    init_deg<<<nodeBlocks, 256, 0, stream>>>(dis);
    count_deg<<<edgeBlocks, 256, 0, stream>>>(ei, dis);
    make_dis<<<nodeBlocks, 256, 0, stream>>>(dis);

    // 5. l1
    l1_kernel<<<featBlocks, 256, 0, stream>>>(A, sdi, l1_W, l1_b, B);

    // 6. zero accumulators
    hipMemsetAsync(A, 0, (size_t)N_NODES * 64 * sizeof(float), stream);
    hipMemsetAsync(acc2, 0, (size_t)(50000 + 500 + 500) * sizeof(float), stream);

    // 7-9. GCN1
    gcn_xform<<<featBlocks, 256, 0, stream>>>(B, g1_W, dis, C);
    scatter64<<<scatBlocks, 256, 0, stream>>>(ei, C, A);
    fin1<<<featBlocks, 256, 0, stream>>>(A, C, dis, g1_b, B);

    // 10-11. GCN2
    gcn2_xform<<<nodeBlocks, 256, 0, stream>>>(B, g2_W, dis, s2);
    scatter1f<<<edgeBlocks, 256, 0, stream>>>(ei, s2, acc2);

    // 12. pool
    finpool<<<nodeBlocks, 256, 0, stream>>>(acc2, s2, dis, g2_b, batch, gsum, gcnt);
    pooldiv<<<2, 256, 0, stream>>>(gsum, gcnt, out);
}

// Round 3
// 1050.188 us; speedup vs baseline: 1.9767x; 1.0535x over previous
//
#include <hip/hip_runtime.h>
#include <hip/hip_bf16.h>

#define N_NODES 50000
#define T_SEQ 24
#define D_IN 16
#define H_DIM 64
#define SD 9
#define E_EDGES 1600000
#define NUM_GRAPHS 500

typedef _Float16 half8 __attribute__((ext_vector_type(8)));
typedef _Float16 half4 __attribute__((ext_vector_type(4)));
typedef float floatx4 __attribute__((ext_vector_type(4)));

__device__ __forceinline__ float fsig(float x) { return 1.0f / (1.0f + __expf(-x)); }
__device__ __forceinline__ float ftanh(float x) { return 1.0f - 2.0f / (1.0f + __expf(2.0f * x)); }

// ---------------------------------------------------------------------------
// MFMA LSTM, v2. Block = 64 nodes, 4 waves.
//  - x slab (64 nodes x 24 t x 16 d) preloaded coalesced into LDS as f16 (48KB)
//  - h double-buffered in LDS (8KB x2) -> ONE barrier per timestep
//  - weights as f16 B-fragments in VGPRs (loaded once, reused 24 steps)
//  - all LDS addresses precomputed; t-loop unrolled with static buffer ping-pong
// ---------------------------------------------------------------------------
__global__ __launch_bounds__(256, 2) void lstm_mfma(
    const float* __restrict__ x,
    const float* __restrict__ W_ih, const float* __restrict__ W_hh,
    const float* __restrict__ b_ih, const float* __restrict__ b_hh,
    float* __restrict__ hout)
{
    // smem layout (f16 elems): hbuf0 [0,4096), hbuf1 [4096,8192), xbuf [8192, 8192+24576)
    __shared__ _Float16 smem[8192 + 24 * 64 * 16];
    _Float16* hb0 = smem;
    _Float16* hb1 = smem + 4096;
    _Float16* xbuf = smem + 8192;   // [t][n][d] f16

    const int tid  = threadIdx.x;
    const int lane = tid & 63;
    const int w    = tid >> 6;      // wave id: unit quarter
    const int lr   = lane & 15;     // row/col within 16x16 tile
    const int lg   = lane >> 4;     // k-group (A/B) or row-group (D)
    const int nbase = blockIdx.x * 64;

    // ---- B fragments (weights), loaded once ----
    half8 bw[4][3];
    float bias[4];
#pragma unroll
    for (int ct = 0; ct < 4; ct++) {
        const int r = ct * 64 + w * 16 + lr;
        bias[ct] = b_ih[r] + b_hh[r];
#pragma unroll
        for (int kt = 0; kt < 2; kt++) {
            const float* p = W_hh + r * 64 + kt * 32 + 8 * lg;
            half8 f;
#pragma unroll
            for (int e = 0; e < 8; e++) f[e] = (_Float16)p[e];
            bw[ct][kt] = f;
        }
        half8 f = {(_Float16)0, (_Float16)0, (_Float16)0, (_Float16)0,
                   (_Float16)0, (_Float16)0, (_Float16)0, (_Float16)0};
        if (lg < 2) {
            const float* p = W_ih + r * 16 + 8 * lg;
#pragma unroll
            for (int e = 0; e < 8; e++) f[e] = (_Float16)p[e];
        }
        bw[ct][2] = f;
    }

    // ---- stage x slab: 64 nodes * 384 floats, contiguous & coalesced ----
#pragma unroll
    for (int it = 0; it < 24; it++) {
        const int f4 = tid + it * 256;          // float4 index within slab
        const int fi = f4 * 4;                  // float index
        const int n  = fi / 384;
        const int rem = fi - n * 384;
        const int t  = rem >> 4;
        const int d  = rem & 15;
        const int gn = (nbase + n < N_NODES) ? nbase + n : N_NODES - 1;
        const float4 v = *reinterpret_cast<const float4*>(x + (size_t)gn * 384 + rem);
        half4 hv = {(_Float16)v.x, (_Float16)v.y, (_Float16)v.z, (_Float16)v.w};
        *reinterpret_cast<half4*>(&xbuf[(t * 64 + n) * 16 + d]) = hv;
    }
    // zero h state (buffer 0)
    for (int i = tid; i < 4096; i += 256) hb0[i] = (_Float16)0.0f;
    __syncthreads();

    // ---- precomputed addresses ----
    // h-read (A frag): per rt,kt: elem = n*64 + 8*((4kt+lg) ^ (n&7)), n = 16rt+lr
    int hra[4][2];
#pragma unroll
    for (int rt = 0; rt < 4; rt++)
#pragma unroll
        for (int kt = 0; kt < 2; kt++) {
            const int n = 16 * rt + lr;
            hra[rt][kt] = n * 64 + 8 * ((4 * kt + lg) ^ (n & 7));
        }
    // x-read: elem = (t*64 + n)*16 + 8*(lg&1)  (lanes lg>=2 read dup, B is 0 there)
    int xra[4];
#pragma unroll
    for (int rt = 0; rt < 4; rt++)
        xra[rt] = (16 * rt + lr) * 16 + 8 * (lg & 1);
    // h-write (D frag): unit u = w*16+lr, node n = 16rt + 4lg + j
    const int u = w * 16 + lr;
    int hwa[4][4];
#pragma unroll
    for (int rt = 0; rt < 4; rt++)
#pragma unroll
        for (int j = 0; j < 4; j++) {
            const int n = 16 * rt + 4 * lg + j;
            hwa[rt][j] = n * 64 + (u & 7) + 8 * ((u >> 3) ^ (n & 7));
        }

    float c_reg[4][4];
#pragma unroll
    for (int rt = 0; rt < 4; rt++)
#pragma unroll
        for (int j = 0; j < 4; j++) c_reg[rt][j] = 0.0f;

    // ---- one timestep ----
    auto step = [&](int t, _Float16* hR, _Float16* hW) {
        floatx4 acc[4][4];
#pragma unroll
        for (int rt = 0; rt < 4; rt++)
#pragma unroll
            for (int ct = 0; ct < 4; ct++) {
                floatx4 a = {bias[ct], bias[ct], bias[ct], bias[ct]};
                acc[rt][ct] = a;
            }
        // x A-frags
        half8 ax[4];
#pragma unroll
        for (int rt = 0; rt < 4; rt++)
            ax[rt] = *reinterpret_cast<const half8*>(&xbuf[t * 1024 + xra[rt]]);
        // h-part MFMAs
#pragma unroll
        for (int kt = 0; kt < 2; kt++) {
            half8 ah[4];
#pragma unroll
            for (int rt = 0; rt < 4; rt++)
                ah[rt] = *reinterpret_cast<const half8*>(&hR[hra[rt][kt]]);
#pragma unroll
            for (int rt = 0; rt < 4; rt++)
#pragma unroll
                for (int ct = 0; ct < 4; ct++)
                    acc[rt][ct] = __builtin_amdgcn_mfma_f32_16x16x32_f16(
                        ah[rt], bw[ct][kt], acc[rt][ct], 0, 0, 0);
        }
        // x-part MFMAs
#pragma unroll
        for (int rt = 0; rt < 4; rt++)
#pragma unroll
            for (int ct = 0; ct < 4; ct++)
                acc[rt][ct] = __builtin_amdgcn_mfma_f32_16x16x32_f16(
                    ax[rt], bw[ct][2], acc[rt][ct], 0, 0, 0);

        // epilogue: gates, c update, h write (to the OTHER buffer)
#pragma unroll
        for (int rt = 0; rt < 4; rt++) {
#pragma unroll
            for (int j = 0; j < 4; j++) {
                const float pi = acc[rt][0][j];
                const float pf = acc[rt][1][j];
                const float pg = acc[rt][2][j];
                const float po = acc[rt][3][j];
                const float ig = fsig(pi);
                const float fg = fsig(pf);
                const float gg = ftanh(pg);
                const float og = fsig(po);
                const float cv = fg * c_reg[rt][j] + ig * gg;
                c_reg[rt][j] = cv;
                const float hv = og * ftanh(cv);
                hW[hwa[rt][j]] = (_Float16)hv;
                if (t == T_SEQ - 1) {
                    const int gn = nbase + 16 * rt + 4 * lg + j;
                    if (gn < N_NODES) hout[(size_t)gn * H_DIM + u] = hv;
                }
            }
        }
        __syncthreads();
    };

    for (int tb = 0; tb < 6; tb++) {
        const int t0 = tb * 4;
        step(t0 + 0, hb0, hb1);
        step(t0 + 1, hb1, hb0);
        step(t0 + 2, hb0, hb1);
        step(t0 + 3, hb1, hb0);
    }
}

// ---------------------------------------------------------------------------
// Degree / normalization
// ---------------------------------------------------------------------------
__global__ void init_deg(float* __restrict__ deg) {
    int i = blockIdx.x * 256 + threadIdx.x;
    if (i < N_NODES) deg[i] = 1.0f;
}

__global__ void count_deg(const int* __restrict__ ei, float* __restrict__ deg) {
    int e = blockIdx.x * 256 + threadIdx.x;
    if (e < E_EDGES) {
        int c = ei[E_EDGES + e];
        if ((unsigned)c < N_NODES) atomicAdd(&deg[c], 1.0f);
    }
}

__global__ void make_dis(float* __restrict__ dis) {
    int i = blockIdx.x * 256 + threadIdx.x;
    if (i < N_NODES) dis[i] = rsqrtf(dis[i]);
}

// ---------------------------------------------------------------------------
__global__ void l1_kernel(const float* __restrict__ h, const float* __restrict__ sdi,
                          const float* __restrict__ W, const float* __restrict__ b,
                          float* __restrict__ z)
{
    int idx = blockIdx.x * 256 + threadIdx.x;
    int n = idx >> 6, o = idx & 63;
    if (n >= N_NODES) return;
    const float* hr = h + (size_t)n * 64;
    const float* sr = sdi + (size_t)n * SD;
    const float* wr = W + o * (H_DIM + SD);
    float acc = b[o];
#pragma unroll
    for (int j = 0; j < 64; j++) acc += wr[j] * hr[j];
#pragma unroll
    for (int j = 0; j < SD; j++) acc += wr[64 + j] * sr[j];
    z[idx] = acc;
}

__global__ void gcn_xform(const float* __restrict__ z, const float* __restrict__ W,
                          const float* __restrict__ dis, float* __restrict__ m)
{
    int idx = blockIdx.x * 256 + threadIdx.x;
    int n = idx >> 6, o = idx & 63;
    if (n >= N_NODES) return;
    const float* zr = z + (size_t)n * 64;
    const float* wr = W + o * 64;
    float acc = 0.0f;
#pragma unroll
    for (int j = 0; j < 64; j++) acc += wr[j] * zr[j];
    m[idx] = acc * dis[n];
}

__global__ void scatter64(const int* __restrict__ ei, const float* __restrict__ m,
                          float* __restrict__ acc)
{
    const int EPW = 4;
    int wid = (blockIdx.x * blockDim.x + threadIdx.x) >> 6;
    int f = threadIdx.x & 63;
    int e0 = wid * EPW;
    int e1 = min(e0 + EPW, E_EDGES);
    for (int e = e0; e < e1; e++) {
        int r = ei[e];
        int cd = ei[E_EDGES + e];
        if ((unsigned)r < N_NODES && (unsigned)cd < N_NODES)
            atomicAdd(&acc[(size_t)cd * 64 + f], m[(size_t)r * 64 + f]);
    }
}

__global__ void fin1(const float* __restrict__ accb, const float* __restrict__ m,
                     const float* __restrict__ dis, const float* __restrict__ b,
                     float* __restrict__ z1)
{
    int idx = blockIdx.x * 256 + threadIdx.x;
    int n = idx >> 6, o = idx & 63;
    if (n >= N_NODES) return;
    float v = dis[n] * (accb[idx] + m[idx]) + b[o];
    z1[idx] = v > 0.0f ? v : 0.0f;
}

__global__ void gcn2_xform(const float* __restrict__ z1, const float* __restrict__ W2,
                           const float* __restrict__ dis, float* __restrict__ s2)
{
    int n = blockIdx.x * 256 + threadIdx.x;
    if (n >= N_NODES) return;
    const float* zr = z1 + (size_t)n * 64;
    float acc = 0.0f;
#pragma unroll
    for (int j = 0; j < 64; j += 4) {
        float4 v = *reinterpret_cast<const float4*>(zr + j);
        acc += v.x * W2[j] + v.y * W2[j + 1] + v.z * W2[j + 2] + v.w * W2[j + 3];
    }
    s2[n] = acc * dis[n];
}

__global__ void scatter1f(const int* __restrict__ ei, const float* __restrict__ s2,
                          float* __restrict__ acc2)
{
    int e = blockIdx.x * 256 + threadIdx.x;
    if (e < E_EDGES) {
        int r = ei[e];
        int cd = ei[E_EDGES + e];
        if ((unsigned)r < N_NODES && (unsigned)cd < N_NODES)
            atomicAdd(&acc2[cd], s2[r]);
    }
}

__global__ void finpool(const float* __restrict__ acc2, const float* __restrict__ s2,
                        const float* __restrict__ dis, const float* __restrict__ b2,
                        const int* __restrict__ batch,
                        float* __restrict__ gsum, float* __restrict__ gcnt)
{
    int n = blockIdx.x * 256 + threadIdx.x;
    if (n >= N_NODES) return;
    float z2 = dis[n] * (acc2[n] + s2[n]) + b2[0];
    int g = batch[n];
    if ((unsigned)g < NUM_GRAPHS) {
        atomicAdd(&gsum[g], z2);
        atomicAdd(&gcnt[g], 1.0f);
    }
}

__global__ void pooldiv(const float* __restrict__ gsum, const float* __restrict__ gcnt,
                        float* __restrict__ out)
{
    int g = blockIdx.x * 256 + threadIdx.x;
    if (g < NUM_GRAPHS) out[g] = gsum[g] / fmaxf(gcnt[g], 1.0f);
}

// ---------------------------------------------------------------------------
extern "C" void kernel_launch(void* const* d_in, const int* in_sizes, int n_in,
                              void* d_out, int out_size, void* d_ws, size_t ws_size,
                              hipStream_t stream)
{
    const float* x     = (const float*)d_in[0];
    const float* sdi   = (const float*)d_in[1];
    const int*   ei    = (const int*)d_in[2];
    const int*   batch = (const int*)d_in[3];
    const float* W_ih  = (const float*)d_in[4];
    const float* W_hh  = (const float*)d_in[5];
    const float* b_ih  = (const float*)d_in[6];
    const float* b_hh  = (const float*)d_in[7];
    const float* l1_W  = (const float*)d_in[8];
    const float* l1_b  = (const float*)d_in[9];
    const float* g1_W  = (const float*)d_in[10];
    const float* g1_b  = (const float*)d_in[11];
    const float* g2_W  = (const float*)d_in[12];
    const float* g2_b  = (const float*)d_in[13];
    float* out = (float*)d_out;

    float* ws   = (float*)d_ws;
    float* A    = ws;                 // lstm h, then gcn1 scatter accumulator
    float* B    = ws + 3200000;       // z, then z1 (in place)
    float* C    = ws + 6400000;       // m = dis * (z @ W1^T)
    float* dis  = ws + 9600000;
    float* s2   = dis + 50000;
    float* acc2 = s2 + 50000;
    float* gsum = acc2 + 50000;
    float* gcnt = gsum + 500;

    const int nodeBlocks  = (N_NODES + 255) / 256;
    const int featBlocks  = (N_NODES * 64 + 255) / 256;
    const int edgeBlocks  = (E_EDGES + 255) / 256;
    const int scatBlocks  = ((E_EDGES + 3) / 4 * 64 + 255) / 256;

    // 1. LSTM -> A
    lstm_mfma<<<(N_NODES + 63) / 64, 256, 0, stream>>>(x, W_ih, W_hh, b_ih, b_hh, A);

    // 2-4. degree -> dis
    init_deg<<<nodeBlocks, 256, 0, stream>>>(dis);
    count_deg<<<edgeBlocks, 256, 0, stream>>>(ei, dis);
    make_dis<<<nodeBlocks, 256, 0, stream>>>(dis);

    // 5. l1
    l1_kernel<<<featBlocks, 256, 0, stream>>>(A, sdi, l1_W, l1_b, B);

    // 6. zero accumulators
    hipMemsetAsync(A, 0, (size_t)N_NODES * 64 * sizeof(float), stream);
    hipMemsetAsync(acc2, 0, (size_t)(50000 + 500 + 500) * sizeof(float), stream);

    // 7-9. GCN1
    gcn_xform<<<featBlocks, 256, 0, stream>>>(B, g1_W, dis, C);
    scatter64<<<scatBlocks, 256, 0, stream>>>(ei, C, A);
    fin1<<<featBlocks, 256, 0, stream>>>(A, C, dis, g1_b, B);

    // 10-11. GCN2
    gcn2_xform<<<nodeBlocks, 256, 0, stream>>>(B, g2_W, dis, s2);
    scatter1f<<<edgeBlocks, 256, 0, stream>>>(ei, s2, acc2);

    // 12. pool
    finpool<<<nodeBlocks, 256, 0, stream>>>(acc2, s2, dis, g2_b, batch, gsum, gcnt);
    pooldiv<<<2, 256, 0, stream>>>(gsum, gcnt, out);
}

// Round 4
// 829.204 us; speedup vs baseline: 2.5035x; 1.2665x over previous
//
#include <hip/hip_runtime.h>
#include <hip/hip_bf16.h>

#define N_NODES 50000
#define T_SEQ 24
#define D_IN 16
#define H_DIM 64
#define SD 9
#define E_EDGES 1600000
#define NUM_GRAPHS 500

typedef _Float16 half8 __attribute__((ext_vector_type(8)));
typedef _Float16 half4 __attribute__((ext_vector_type(4)));
typedef float floatx4 __attribute__((ext_vector_type(4)));

__device__ __forceinline__ float fsig(float x) { return 1.0f / (1.0f + __expf(-x)); }
__device__ __forceinline__ float ftanh(float x) { return 1.0f - 2.0f / (1.0f + __expf(2.0f * x)); }

// ---------------------------------------------------------------------------
// MFMA LSTM (unchanged from round 3). Block = 64 nodes, 4 waves.
// ---------------------------------------------------------------------------
__global__ __launch_bounds__(256, 2) void lstm_mfma(
    const float* __restrict__ x,
    const float* __restrict__ W_ih, const float* __restrict__ W_hh,
    const float* __restrict__ b_ih, const float* __restrict__ b_hh,
    float* __restrict__ hout)
{
    __shared__ _Float16 smem[8192 + 24 * 64 * 16];
    _Float16* hb0 = smem;
    _Float16* hb1 = smem + 4096;
    _Float16* xbuf = smem + 8192;   // [t][n][d] f16

    const int tid  = threadIdx.x;
    const int lane = tid & 63;
    const int w    = tid >> 6;
    const int lr   = lane & 15;
    const int lg   = lane >> 4;
    const int nbase = blockIdx.x * 64;

    half8 bw[4][3];
    float bias[4];
#pragma unroll
    for (int ct = 0; ct < 4; ct++) {
        const int r = ct * 64 + w * 16 + lr;
        bias[ct] = b_ih[r] + b_hh[r];
#pragma unroll
        for (int kt = 0; kt < 2; kt++) {
            const float* p = W_hh + r * 64 + kt * 32 + 8 * lg;
            half8 f;
#pragma unroll
            for (int e = 0; e < 8; e++) f[e] = (_Float16)p[e];
            bw[ct][kt] = f;
        }
        half8 f = {(_Float16)0, (_Float16)0, (_Float16)0, (_Float16)0,
                   (_Float16)0, (_Float16)0, (_Float16)0, (_Float16)0};
        if (lg < 2) {
            const float* p = W_ih + r * 16 + 8 * lg;
#pragma unroll
            for (int e = 0; e < 8; e++) f[e] = (_Float16)p[e];
        }
        bw[ct][2] = f;
    }

#pragma unroll
    for (int it = 0; it < 24; it++) {
        const int f4 = tid + it * 256;
        const int fi = f4 * 4;
        const int n  = fi / 384;
        const int rem = fi - n * 384;
        const int t  = rem >> 4;
        const int d  = rem & 15;
        const int gn = (nbase + n < N_NODES) ? nbase + n : N_NODES - 1;
        const float4 v = *reinterpret_cast<const float4*>(x + (size_t)gn * 384 + rem);
        half4 hv = {(_Float16)v.x, (_Float16)v.y, (_Float16)v.z, (_Float16)v.w};
        *reinterpret_cast<half4*>(&xbuf[(t * 64 + n) * 16 + d]) = hv;
    }
    for (int i = tid; i < 4096; i += 256) hb0[i] = (_Float16)0.0f;
    __syncthreads();

    int hra[4][2];
#pragma unroll
    for (int rt = 0; rt < 4; rt++)
#pragma unroll
        for (int kt = 0; kt < 2; kt++) {
            const int n = 16 * rt + lr;
            hra[rt][kt] = n * 64 + 8 * ((4 * kt + lg) ^ (n & 7));
        }
    int xra[4];
#pragma unroll
    for (int rt = 0; rt < 4; rt++)
        xra[rt] = (16 * rt + lr) * 16 + 8 * (lg & 1);
    const int u = w * 16 + lr;
    int hwa[4][4];
#pragma unroll
    for (int rt = 0; rt < 4; rt++)
#pragma unroll
        for (int j = 0; j < 4; j++) {
            const int n = 16 * rt + 4 * lg + j;
            hwa[rt][j] = n * 64 + (u & 7) + 8 * ((u >> 3) ^ (n & 7));
        }

    float c_reg[4][4];
#pragma unroll
    for (int rt = 0; rt < 4; rt++)
#pragma unroll
        for (int j = 0; j < 4; j++) c_reg[rt][j] = 0.0f;

    auto step = [&](int t, _Float16* hR, _Float16* hW) {
        floatx4 acc[4][4];
#pragma unroll
        for (int rt = 0; rt < 4; rt++)
#pragma unroll
            for (int ct = 0; ct < 4; ct++) {
                floatx4 a = {bias[ct], bias[ct], bias[ct], bias[ct]};
                acc[rt][ct] = a;
            }
        half8 ax[4];
#pragma unroll
        for (int rt = 0; rt < 4; rt++)
            ax[rt] = *reinterpret_cast<const half8*>(&xbuf[t * 1024 + xra[rt]]);
#pragma unroll
        for (int kt = 0; kt < 2; kt++) {
            half8 ah[4];
#pragma unroll
            for (int rt = 0; rt < 4; rt++)
                ah[rt] = *reinterpret_cast<const half8*>(&hR[hra[rt][kt]]);
#pragma unroll
            for (int rt = 0; rt < 4; rt++)
#pragma unroll
                for (int ct = 0; ct < 4; ct++)
                    acc[rt][ct] = __builtin_amdgcn_mfma_f32_16x16x32_f16(
                        ah[rt], bw[ct][kt], acc[rt][ct], 0, 0, 0);
        }
#pragma unroll
        for (int rt = 0; rt < 4; rt++)
#pragma unroll
            for (int ct = 0; ct < 4; ct++)
                acc[rt][ct] = __builtin_amdgcn_mfma_f32_16x16x32_f16(
                    ax[rt], bw[ct][2], acc[rt][ct], 0, 0, 0);

#pragma unroll
        for (int rt = 0; rt < 4; rt++) {
#pragma unroll
            for (int j = 0; j < 4; j++) {
                const float pi = acc[rt][0][j];
                const float pf = acc[rt][1][j];
                const float pg = acc[rt][2][j];
                const float po = acc[rt][3][j];
                const float ig = fsig(pi);
                const float fg = fsig(pf);
                const float gg = ftanh(pg);
                const float og = fsig(po);
                const float cv = fg * c_reg[rt][j] + ig * gg;
                c_reg[rt][j] = cv;
                const float hv = og * ftanh(cv);
                hW[hwa[rt][j]] = (_Float16)hv;
                if (t == T_SEQ - 1) {
                    const int gn = nbase + 16 * rt + 4 * lg + j;
                    if (gn < N_NODES) hout[(size_t)gn * H_DIM + u] = hv;
                }
            }
        }
        __syncthreads();
    };

    for (int tb = 0; tb < 6; tb++) {
        const int t0 = tb * 4;
        step(t0 + 0, hb0, hb1);
        step(t0 + 1, hb1, hb0);
        step(t0 + 2, hb0, hb1);
        step(t0 + 3, hb1, hb0);
    }
}

// ---------------------------------------------------------------------------
// CSR build: histogram -> scan -> fill
// ---------------------------------------------------------------------------
__global__ void count_deg(const int* __restrict__ ei, int* __restrict__ cnt) {
    int e = blockIdx.x * 256 + threadIdx.x;
    if (e < E_EDGES) {
        int c = ei[E_EDGES + e];
        if ((unsigned)c < N_NODES) atomicAdd(&cnt[c], 1);
    }
}

__global__ void make_dis(const int* __restrict__ cnt, float* __restrict__ dis) {
    int i = blockIdx.x * 256 + threadIdx.x;
    if (i < N_NODES) dis[i] = rsqrtf((float)(cnt[i] + 1));  // +1 self-loop
}

// single-block exclusive scan over cnt -> ptr (and cursor copy)
__global__ __launch_bounds__(1024) void scan_csr(const int* __restrict__ cnt,
                                                 int* __restrict__ ptr,
                                                 int* __restrict__ cursor)
{
    __shared__ int wsum[16];
    __shared__ int carry_s;
    const int tid = threadIdx.x;
    const int lane = tid & 63;
    const int wv = tid >> 6;
    if (tid == 0) carry_s = 0;
    __syncthreads();
    for (int base = 0; base < N_NODES; base += 1024) {
        const int i = base + tid;
        const int orig = (i < N_NODES) ? cnt[i] : 0;
        int v = orig;
#pragma unroll
        for (int d = 1; d < 64; d <<= 1) {
            int nb = __shfl_up(v, d, 64);
            if (lane >= d) v += nb;
        }
        if (lane == 63) wsum[wv] = v;
        __syncthreads();
        if (wv == 0) {
            int s = (lane < 16) ? wsum[lane] : 0;
#pragma unroll
            for (int d = 1; d < 16; d <<= 1) {
                int nb = __shfl_up(s, d, 64);
                if (lane >= d) s += nb;
            }
            if (lane < 16) wsum[lane] = s;
        }
        __syncthreads();
        const int waveoff = (wv > 0) ? wsum[wv - 1] : 0;
        const int excl = carry_s + waveoff + v - orig;
        if (i < N_NODES) { ptr[i] = excl; cursor[i] = excl; }
        __syncthreads();
        if (tid == 1023) carry_s += wsum[15];
        __syncthreads();
    }
    if (tid == 0) ptr[N_NODES] = carry_s;
}

__global__ void fill_csr(const int* __restrict__ ei, int* __restrict__ cursor,
                         int* __restrict__ csr)
{
    int e = blockIdx.x * 256 + threadIdx.x;
    if (e < E_EDGES) {
        int r = ei[e];
        int c = ei[E_EDGES + e];
        if ((unsigned)r < N_NODES && (unsigned)c < N_NODES) {
            int slot = atomicAdd(&cursor[c], 1);
            csr[slot] = r;
        }
    }
}

// ---------------------------------------------------------------------------
__global__ void l1_kernel(const float* __restrict__ h, const float* __restrict__ sdi,
                          const float* __restrict__ W, const float* __restrict__ b,
                          float* __restrict__ z)
{
    int idx = blockIdx.x * 256 + threadIdx.x;
    int n = idx >> 6, o = idx & 63;
    if (n >= N_NODES) return;
    const float* hr = h + (size_t)n * 64;
    const float* sr = sdi + (size_t)n * SD;
    const float* wr = W + o * (H_DIM + SD);
    float acc = b[o];
#pragma unroll
    for (int j = 0; j < 64; j++) acc += wr[j] * hr[j];
#pragma unroll
    for (int j = 0; j < SD; j++) acc += wr[64 + j] * sr[j];
    z[idx] = acc;
}

__global__ void gcn_xform(const float* __restrict__ z, const float* __restrict__ W,
                          const float* __restrict__ dis, float* __restrict__ m)
{
    int idx = blockIdx.x * 256 + threadIdx.x;
    int n = idx >> 6, o = idx & 63;
    if (n >= N_NODES) return;
    const float* zr = z + (size_t)n * 64;
    const float* wr = W + o * 64;
    float acc = 0.0f;
#pragma unroll
    for (int j = 0; j < 64; j++) acc += wr[j] * zr[j];
    m[idx] = acc * dis[n];
}

// wave per dst, lane = feature: out[dst][f] = sum_{src in in(dst)} m[src][f]
__global__ __launch_bounds__(256) void gather64(
    const int* __restrict__ ptr, const int* __restrict__ csr,
    const float* __restrict__ m, float* __restrict__ out)
{
    const int wid = __builtin_amdgcn_readfirstlane(
        (blockIdx.x * 256 + threadIdx.x) >> 6);
    const int f = threadIdx.x & 63;
    if (wid >= N_NODES) return;
    const int b = ptr[wid];
    const int e = ptr[wid + 1];
    float a0 = 0.0f, a1 = 0.0f, a2 = 0.0f, a3 = 0.0f;
    int i = b;
    for (; i + 4 <= e; i += 4) {
        const int s0 = csr[i], s1 = csr[i + 1], s2 = csr[i + 2], s3 = csr[i + 3];
        a0 += m[(size_t)s0 * 64 + f];
        a1 += m[(size_t)s1 * 64 + f];
        a2 += m[(size_t)s2 * 64 + f];
        a3 += m[(size_t)s3 * 64 + f];
    }
    for (; i < e; i++) a0 += m[(size_t)csr[i] * 64 + f];
    out[(size_t)wid * 64 + f] = (a0 + a1) + (a2 + a3);
}

__global__ void fin1(const float* __restrict__ accb, const float* __restrict__ m,
                     const float* __restrict__ dis, const float* __restrict__ b,
                     float* __restrict__ z1)
{
    int idx = blockIdx.x * 256 + threadIdx.x;
    int n = idx >> 6, o = idx & 63;
    if (n >= N_NODES) return;
    float v = dis[n] * (accb[idx] + m[idx]) + b[o];
    z1[idx] = v > 0.0f ? v : 0.0f;
}

__global__ void gcn2_xform(const float* __restrict__ z1, const float* __restrict__ W2,
                           const float* __restrict__ dis, float* __restrict__ s2)
{
    int n = blockIdx.x * 256 + threadIdx.x;
    if (n >= N_NODES) return;
    const float* zr = z1 + (size_t)n * 64;
    float acc = 0.0f;
#pragma unroll
    for (int j = 0; j < 64; j += 4) {
        float4 v = *reinterpret_cast<const float4*>(zr + j);
        acc += v.x * W2[j] + v.y * W2[j + 1] + v.z * W2[j + 2] + v.w * W2[j + 3];
    }
    s2[n] = acc * dis[n];
}

// fused: gather layer-2 messages + finalize z2 + pool atomics
__global__ void gather2fin(const int* __restrict__ ptr, const int* __restrict__ csr,
                           const float* __restrict__ s2, const float* __restrict__ dis,
                           const float* __restrict__ b2, const int* __restrict__ batch,
                           float* __restrict__ gsum, float* __restrict__ gcnt)
{
    int n = blockIdx.x * 256 + threadIdx.x;
    if (n >= N_NODES) return;
    const int b = ptr[n];
    const int e = ptr[n + 1];
    float a0 = 0.0f, a1 = 0.0f, a2 = 0.0f, a3 = 0.0f;
    int i = b;
    for (; i + 4 <= e; i += 4) {
        a0 += s2[csr[i]];
        a1 += s2[csr[i + 1]];
        a2 += s2[csr[i + 2]];
        a3 += s2[csr[i + 3]];
    }
    for (; i < e; i++) a0 += s2[csr[i]];
    const float z2 = dis[n] * (((a0 + a1) + (a2 + a3)) + s2[n]) + b2[0];
    const int g = batch[n];
    if ((unsigned)g < NUM_GRAPHS) {
        atomicAdd(&gsum[g], z2);
        atomicAdd(&gcnt[g], 1.0f);
    }
}

__global__ void pooldiv(const float* __restrict__ gsum, const float* __restrict__ gcnt,
                        float* __restrict__ out)
{
    int g = blockIdx.x * 256 + threadIdx.x;
    if (g < NUM_GRAPHS) out[g] = gsum[g] / fmaxf(gcnt[g], 1.0f);
}

// ---------------------------------------------------------------------------
extern "C" void kernel_launch(void* const* d_in, const int* in_sizes, int n_in,
                              void* d_out, int out_size, void* d_ws, size_t ws_size,
                              hipStream_t stream)
{
    const float* x     = (const float*)d_in[0];
    const float* sdi   = (const float*)d_in[1];
    const int*   ei    = (const int*)d_in[2];
    const int*   batch = (const int*)d_in[3];
    const float* W_ih  = (const float*)d_in[4];
    const float* W_hh  = (const float*)d_in[5];
    const float* b_ih  = (const float*)d_in[6];
    const float* b_hh  = (const float*)d_in[7];
    const float* l1_W  = (const float*)d_in[8];
    const float* l1_b  = (const float*)d_in[9];
    const float* g1_W  = (const float*)d_in[10];
    const float* g1_b  = (const float*)d_in[11];
    const float* g2_W  = (const float*)d_in[12];
    const float* g2_b  = (const float*)d_in[13];
    float* out = (float*)d_out;

    // workspace layout
    float* ws   = (float*)d_ws;
    float* A    = ws;                 // lstm h -> (after l1) gather1 output
    float* B    = ws + 3200000;       // z -> z1 (in place)
    float* C    = ws + 6400000;       // m = dis * (z @ W1^T)
    float* dis  = ws + 9600000;
    float* s2   = dis + 50000;
    float* gsum = s2 + 50000;
    float* gcnt = gsum + 500;
    int* cnt    = (int*)(gcnt + 500);
    int* ptr    = cnt + 50000;        // 50001 entries
    int* cursor = ptr + 50001;
    int* csr    = cursor + 50000;     // 1.6M entries

    const int nodeBlocks = (N_NODES + 255) / 256;
    const int featBlocks = (N_NODES * 64 + 255) / 256;   // 12500
    const int edgeBlocks = (E_EDGES + 255) / 256;

    // 1. LSTM -> A
    lstm_mfma<<<(N_NODES + 63) / 64, 256, 0, stream>>>(x, W_ih, W_hh, b_ih, b_hh, A);

    // 2. CSR build + normalization
    hipMemsetAsync(cnt, 0, 50000 * sizeof(int), stream);
    hipMemsetAsync(gsum, 0, 1000 * sizeof(float), stream);
    count_deg<<<edgeBlocks, 256, 0, stream>>>(ei, cnt);
    make_dis<<<nodeBlocks, 256, 0, stream>>>(cnt, dis);
    scan_csr<<<1, 1024, 0, stream>>>(cnt, ptr, cursor);
    fill_csr<<<edgeBlocks, 256, 0, stream>>>(ei, cursor, csr);

    // 3. l1: (A, sdi) -> B
    l1_kernel<<<featBlocks, 256, 0, stream>>>(A, sdi, l1_W, l1_b, B);

    // 4. GCN1: m -> C, gather -> A, finalize -> B
    gcn_xform<<<featBlocks, 256, 0, stream>>>(B, g1_W, dis, C);
    gather64<<<featBlocks, 256, 0, stream>>>(ptr, csr, C, A);
    fin1<<<featBlocks, 256, 0, stream>>>(A, C, dis, g1_b, B);

    // 5. GCN2 + pool
    gcn2_xform<<<nodeBlocks, 256, 0, stream>>>(B, g2_W, dis, s2);
    gather2fin<<<nodeBlocks, 256, 0, stream>>>(ptr, csr, s2, dis, g2_b, batch, gsum, gcnt);
    pooldiv<<<2, 256, 0, stream>>>(gsum, gcnt, out);
}